// Round 6
// baseline (3614.014 us; speedup 1.0000x reference)
//
#include <hip/hip_runtime.h>
#include <hip/hip_cooperative_groups.h>
#include <math.h>

namespace cg = cooperative_groups;

#define BB 4
#define N0 4096
#define NEWP 1152
#define GD 256
#define HD 128
#define KSEL 64
#define NSTEPS 10
#define NMAX (N0 + NSTEPS*NEWP)   /* 15616 */
#define NNEW (NSTEPS*NEWP)        /* 11520 */

/* ---- workspace layout (float offsets) ---- */
#define OFF_CANVAS 0
#define OFF_MINAB  (OFF_CANVAS + BB*NMAX*3)
#define OFF_MINCD  (OFF_MINAB + BB*NMAX)
#define OFF_GMAX   (OFF_MINCD + BB*NMAX)
#define OFF_H      (OFF_GMAX + BB*GD)
#define OFF_C      (OFF_H + BB*HD)
#define OFF_ACC    (OFF_C + BB*HD)
#define OFF_CENTER (OFF_ACC + 16)
#define OFF_W2T    (OFF_CENTER + 32)
#define OFF_PART   (OFF_W2T + 128*64)
#define OFF_GPART  (OFF_PART + BB*32*8)
#define WS_FLOATS  (OFF_GPART + 32*BB*512)

struct P {
  const float *points, *gt;
  const float *w1,*b1,*w2,*b2,*w3,*b3;
  const float *aw1,*ab1,*aw2,*ab2;
  const float *wih,*whh,*bih,*bhh;
  const float *rw1,*rb1,*rw2,*rb2;
  float *canvas; unsigned *minAB,*minCD,*gmax;
  float *h,*c,*acc,*centerpf,*w2t,*part,*gpart;
  float *out;
};

__device__ __forceinline__ unsigned enc_f(float f){
  unsigned u = __float_as_uint(f);
  return (u & 0x80000000u) ? ~u : (u | 0x80000000u);
}
__device__ __forceinline__ float dec_f(unsigned e){
  unsigned u = (e & 0x80000000u) ? (e & 0x7fffffffu) : ~e;
  return __uint_as_float(u);
}
__device__ __forceinline__ float sigm(float x){ return 1.f/(1.f+expf(-x)); }

/* 512-thread block reductions (8 waves) */
__device__ __forceinline__ float bsum(float v, volatile float* red){
#pragma unroll
  for (int s=32;s>0;s>>=1) v += __shfl_down(v, s, 64);
  int lane = threadIdx.x & 63, w = threadIdx.x >> 6;
  __syncthreads();
  if (lane==0) red[w] = v;
  __syncthreads();
  if (w==0){
    float x = (lane < 8) ? red[lane] : 0.f;
#pragma unroll
    for (int s=4;s>0;s>>=1) x += __shfl_down(x, s, 64);
    if (lane==0) red[0] = x;
  }
  __syncthreads();
  float r = red[0];
  __syncthreads();
  return r;
}
__device__ __forceinline__ float bmax(float v, volatile float* red){
#pragma unroll
  for (int s=32;s>0;s>>=1) v = fmaxf(v, __shfl_down(v, s, 64));
  int lane = threadIdx.x & 63, w = threadIdx.x >> 6;
  __syncthreads();
  if (lane==0) red[w] = v;
  __syncthreads();
  if (w==0){
    float x = (lane < 8) ? red[lane] : -3.4e38f;
#pragma unroll
    for (int s=4;s>0;s>>=1) x = fmaxf(x, __shfl_down(x, s, 64));
    if (lane==0) red[0] = x;
  }
  __syncthreads();
  float r = red[0];
  __syncthreads();
  return r;
}

union Sh {
  struct { float sP[192]; float sF1[64*65]; float sF2[64*129]; } a;  /* ~50KB */
  struct { float sBatt[128]; float red[8]; } b;
  struct { float sV[BB][12]; } l;
  struct { float red[8]; float sC[3]; float sPF[3];
           unsigned cA[2][8]; unsigned cB[2][8];
           int tieCnt; int tieIdx[256]; float sG[512]; } c;
  struct { float sRf[128]; } d;
  struct { float y0[1024], y1[1024], y2[1024], ny[1024]; } ch;
  struct { float red[8]; } r;
};

__global__ __launch_bounds__(512, 1) void mega_kernel(P p)
{
  cg::grid_group grid = cg::this_grid();
  __shared__ Sh sh;
  int blk = blockIdx.x;
  int tid = threadIdx.x;
  int lane = tid & 63;
  int gid = blk*512 + tid;

  /* ---------- setup ---------- */
  if (gid < BB*N0*3){
    int b = gid/(N0*3), r = gid - b*(N0*3);
    p.canvas[(size_t)b*NMAX*3 + r] = p.points[gid];
  }
  if (gid < 2*BB*N0) p.minAB[gid] = 0xFFFFFFFFu;
  if (gid < BB*NNEW + BB*N0) p.minCD[gid] = 0xFFFFFFFFu;
  if (gid < BB*GD) p.gmax[gid] = 0u;
  if (gid < BB*HD){ p.h[gid]=0.f; p.c[gid]=0.f; }
  if (gid < 128*64){ int j=gid>>6, k=gid&63; p.w2t[gid] = p.w2[k*128+j]; }
  grid.sync();

  for (int t=0; t<NSTEPS; t++){
    int N = N0 + t*NEWP;
    int M = (t==0) ? N0 : NEWP;
    int off = (t==0) ? 0 : (N - NEWP);

    /* ---------- phase A: encoder + running gmax (64 pts/block) ---------- */
    int gpb = M >> 6;             /* groups per batch: 64 or 18 */
    int ngroups = gpb*BB;
    if (blk < ngroups){
      int b = blk / gpb, lg = blk - b*gpb;
      int pbase = off + lg*64;
      const float* cb_ = p.canvas + (size_t)b*NMAX*3;
      if (tid < 192) sh.a.sP[tid] = cb_[(size_t)pbase*3 + tid];
      __syncthreads();
      int wv = __builtin_amdgcn_readfirstlane(tid >> 6);   /* wave id 0..7 */
      /* f1: pt = wv+8k, feature j = lane */
#pragma unroll
      for (int k=0;k<8;k++){
        int pt = wv + 8*k;
        float p0 = sh.a.sP[pt*3], p1 = sh.a.sP[pt*3+1], p2 = sh.a.sP[pt*3+2];
        float v = p.b1[lane] + p0*p.w1[lane] + p1*p.w1[64+lane] + p2*p.w1[128+lane];
        sh.a.sF1[pt*65 + lane] = fmaxf(v, 0.f);
      }
      __syncthreads();
      /* f2: pt = lane, feat = wv+8k (wave-uniform -> scalar w2t row) */
#pragma unroll
      for (int k=0;k<16;k++){
        int feat = wv + 8*k;
        const float* wr = p.w2t + feat*64;
        float a2 = p.b2[feat];
#pragma unroll
        for (int kk=0;kk<64;kk++) a2 += sh.a.sF1[lane*65 + kk]*wr[kk];
        sh.a.sF2[lane*129 + feat] = fmaxf(a2, 0.f);
      }
      __syncthreads();
      /* f3: wave wv owns chunk wv (32 outs), lane = pt */
      {
        int chunk = wv;
        float a3[32];
        const float* b3p = p.b3 + chunk*32;
#pragma unroll
        for (int d=0;d<32;d++) a3[d] = b3p[d];
        for (int k=0;k<128;k++){
          float fk = sh.a.sF2[lane*129 + k];
          const float* wr = p.w3 + k*256 + chunk*32;   /* scalar */
#pragma unroll
          for (int d=0;d<32;d++) a3[d] += fk*wr[d];
        }
#pragma unroll
        for (int d=0;d<32;d++){
          float v = a3[d];
#pragma unroll
          for (int s=32;s>0;s>>=1) v = fmaxf(v, __shfl_down(v, s, 64));
          if (lane==0) atomicMax(&p.gmax[b*GD + chunk*32 + d], enc_f(v));
        }
      }
    }
    grid.sync();

    /* ---------- phase B: scores partials (blocks<4*nch) + lstm partials (128..159) ---------- */
    int nch = (N + 511) >> 9;
    if (blk < 4*nch){
      int b = blk / nch, ch = blk - b*nch;
      if (tid < 128){
        float a = p.ab1[tid];
        for (int k=0;k<GD;k++) a += dec_f(p.gmax[b*GD+k]) * p.aw1[(3+k)*128 + tid];
        for (int k=0;k<HD;k++) a += p.h[b*HD+k] * p.aw1[(3+GD+k)*128 + tid];
        sh.b.sBatt[tid] = a;
      }
      __syncthreads();
      int i = ch*512 + tid;
      bool act = i < N;
      float p0=0.f,p1=0.f,p2=0.f,s=-3.4e38f;
      if (act){
        const float* pp = p.canvas + (size_t)(b*NMAX + i)*3;
        p0=pp[0]; p1=pp[1]; p2=pp[2];
        s = p.ab2[0];
        for (int j=0;j<128;j++){
          float v = sh.b.sBatt[j] + p0*p.aw1[j] + p1*p.aw1[128+j] + p2*p.aw1[256+j];
          s += fmaxf(v, 0.f)*p.aw2[j];
        }
      }
      float mb = bmax(s, sh.b.red);
      float e = act ? expf(s - mb) : 0.f;
      float se = bsum(e, sh.b.red);
      float wx = bsum(e*p0, sh.b.red);
      float wy = bsum(e*p1, sh.b.red);
      float wz = bsum(e*p2, sh.b.red);
      if (tid==0){
        float* pr = p.part + (size_t)(b*32 + ch)*8;
        pr[0]=mb; pr[1]=se; pr[2]=wx; pr[3]=wy; pr[4]=wz;
      }
    } else if (blk >= 128 && blk < 160){
      int cc = blk - 128;
      if (tid < BB*12){
        int b = tid/12, j = tid - b*12;
        int r = cc*12 + j;
        sh.l.sV[b][j] = (r < 256) ? dec_f(p.gmax[b*GD + r]) : p.h[b*HD + (r-256)];
      }
      __syncthreads();
      float a0=0.f,a1=0.f,a2=0.f,a3=0.f;
#pragma unroll
      for (int j=0;j<12;j++){
        int r = cc*12 + j;
        const float* wr = (r < 256) ? (p.wih + (size_t)r*512) : (p.whh + (size_t)(r-256)*512);
        float wvv = wr[tid];
        a0 += sh.l.sV[0][j]*wvv; a1 += sh.l.sV[1][j]*wvv;
        a2 += sh.l.sV[2][j]*wvv; a3 += sh.l.sV[3][j]*wvv;
      }
      float* gp = p.gpart + (size_t)cc*(BB*512);
      gp[0*512+tid]=a0; gp[1*512+tid]=a1; gp[2*512+tid]=a2; gp[3*512+tid]=a3;
    }
    grid.sync();

    /* ---------- phase C: center + top-64 + LSTM finish (blocks 0..3) ---------- */
    if (blk < BB){
      int b = blk;
      const float* cv = p.canvas + (size_t)b*NMAX*3;
      float pm=-3.4e38f, pse=0.f, pwx=0.f, pwy=0.f, pwz=0.f;
      if (tid < nch){
        const float* pr = p.part + (size_t)(b*32 + tid)*8;
        pm=pr[0]; pse=pr[1]; pwx=pr[2]; pwy=pr[3]; pwz=pr[4];
      }
      float Mx = bmax(pm, sh.c.red);
      float ww = (tid < nch) ? expf(pm - Mx) : 0.f;
      float se = bsum(pse*ww, sh.c.red);
      float wx = bsum(pwx*ww, sh.c.red);
      float wy = bsum(pwy*ww, sh.c.red);
      float wz = bsum(pwz*ww, sh.c.red);
      if (tid==0){ sh.c.sC[0]=wx/se; sh.c.sC[1]=wy/se; sh.c.sC[2]=wz/se; }
      __syncthreads();
      float cx=sh.c.sC[0], cy=sh.c.sC[1], cz=sh.c.sC[2];
      if (tid<3) p.centerpf[b*3+tid] = sh.c.sC[tid];

      int qm = (N + 511) >> 9;
      unsigned ur[29];
#pragma unroll
      for (int q=0;q<29;q++){
        ur[q] = 0xFFFFFFFFu;
        int i = tid + q*512;
        if (q < qm && i < N){
          const float* pp = cv + (size_t)i*3;
          float dx=pp[0]-cx, dy=pp[1]-cy, dz=pp[2]-cz;
          ur[q] = __float_as_uint(dx*dx + dy*dy + dz*dz);
        }
      }
      /* threshold binary search, 2 bits/iter */
      unsigned T = 0u; int cntBelow = 0; int par = 0;
      int w8 = tid >> 6;
      {
        unsigned cand = 1u<<30;
        unsigned tc = 0;
#pragma unroll
        for (int q=0;q<29;q++) tc += (ur[q] < cand) ? 1u : 0u;
#pragma unroll
        for (int s=32;s>0;s>>=1) tc += __shfl_down(tc, s, 64);
        if (lane==0) sh.c.cA[par][w8] = tc;
        __syncthreads();
        unsigned tot = 0;
#pragma unroll
        for (int i2=0;i2<8;i2++) tot += sh.c.cA[par][i2];
        if ((int)tot < KSEL){ T = cand; cntBelow = (int)tot; }
        par ^= 1;
      }
      for (int bit=29; bit>=1; bit-=2){
        unsigned q1 = 1u<<(bit-1);
        unsigned c1 = T + q1, c2 = T + 2u*q1, c3 = T + 3u*q1;
        unsigned ta = 0, tb = 0;
#pragma unroll
        for (int q=0;q<29;q++){
          unsigned u = ur[q];
          ta += (u < c1 ? 1u : 0u) | (u < c2 ? 0x10000u : 0u);
          tb += (u < c3 ? 1u : 0u);
        }
#pragma unroll
        for (int s=32;s>0;s>>=1){ ta += __shfl_down(ta, s, 64); tb += __shfl_down(tb, s, 64); }
        if (lane==0){ sh.c.cA[par][w8] = ta; sh.c.cB[par][w8] = tb; }
        __syncthreads();
        unsigned sa = 0, sb = 0;
#pragma unroll
        for (int i2=0;i2<8;i2++){ sa += sh.c.cA[par][i2]; sb += sh.c.cB[par][i2]; }
        int n1 = (int)(sa & 0xFFFFu), n2 = (int)(sa >> 16), n3 = (int)sb;
        if (n3 < KSEL){ T = c3; cntBelow = n3; }
        else if (n2 < KSEL){ T = c2; cntBelow = n2; }
        else if (n1 < KSEL){ T = c1; cntBelow = n1; }
        par ^= 1;
      }
      int kneed = KSEL - cntBelow;

      if (tid==0) sh.c.tieCnt = 0;
      __syncthreads();
      float sx=0.f, sy=0.f, sz=0.f;
#pragma unroll
      for (int q=0;q<29;q++){
        unsigned u = ur[q];
        if (u < T){
          const float* pp = cv + (size_t)(tid + q*512)*3;
          sx += pp[0]; sy += pp[1]; sz += pp[2];
        } else if (u == T){
          int pos = atomicAdd(&sh.c.tieCnt, 1);
          if (pos < 256) sh.c.tieIdx[pos] = tid + q*512;
        }
      }
      __syncthreads();
      sx = bsum(sx, sh.c.red);
      sy = bsum(sy, sh.c.red);
      sz = bsum(sz, sh.c.red);
      if (tid==0){
        int mm = sh.c.tieCnt < 256 ? sh.c.tieCnt : 256;
        for (int tt=0; tt<kneed; tt++){
          int best=-1, bi=0x7fffffff;
          for (int q=0;q<mm;q++){ int v = sh.c.tieIdx[q]; if (v < bi){ bi=v; best=q; } }
          if (best >= 0){
            sh.c.tieIdx[best] = 0x7fffffff;
            const float* pp = cv + (size_t)bi*3;
            sx += pp[0]; sy += pp[1]; sz += pp[2];
          }
        }
        sh.c.sPF[0] = sx/KSEL - cx; sh.c.sPF[1] = sy/KSEL - cy; sh.c.sPF[2] = sz/KSEL - cz;
        p.centerpf[16 + b*3 + 0] = sh.c.sPF[0];
        p.centerpf[16 + b*3 + 1] = sh.c.sPF[1];
        p.centerpf[16 + b*3 + 2] = sh.c.sPF[2];
      }
      __syncthreads();
      /* LSTM finish: o = tid (512 gates) */
      {
        float fx = sh.c.sPF[0], fy = sh.c.sPF[1], fz = sh.c.sPF[2];
        float g = p.bih[tid] + p.bhh[tid];
        for (int cc=0; cc<32; cc++) g += p.gpart[(size_t)cc*(BB*512) + b*512 + tid];
        g += cx*p.wih[(size_t)256*512+tid] + cy*p.wih[(size_t)257*512+tid] + cz*p.wih[(size_t)258*512+tid];
        g += fx*p.wih[(size_t)259*512+tid] + fy*p.wih[(size_t)260*512+tid] + fz*p.wih[(size_t)261*512+tid];
        sh.c.sG[tid] = g;
      }
      __syncthreads();
      if (tid < HD){
        float gi=sh.c.sG[tid], gf=sh.c.sG[128+tid], gg=sh.c.sG[256+tid], go=sh.c.sG[384+tid];
        float cn = sigm(gf)*p.c[b*HD+tid] + sigm(gi)*tanhf(gg);
        float hn = sigm(go)*tanhf(cn);
        p.c[b*HD+tid] = cn;
        p.h[b*HD+tid] = hn;
      }
    }
    grid.sync();

    /* ---------- phase D: refine decoder + append (all 256 blocks) ---------- */
    {
      int b = blk >> 6, k2 = blk & 63;
      if (tid < HD){
        float a = p.rb1[tid];
        for (int k=0;k<HD;k++) a += p.h[b*HD+k]*p.rw1[k*HD + tid];
        sh.d.sRf[tid] = fmaxf(a, 0.f);
      }
      __syncthreads();
      if (tid < 54){
        int o = k2*54 + tid;
        float a = p.rb2[o];
        for (int k=0;k<HD;k++) a += sh.d.sRf[k]*p.rw2[(size_t)k*(NEWP*3) + o];
        int pt = N + k2*18 + tid/3;
        p.canvas[((size_t)b*NMAX + pt)*3 + (tid%3)] = a*0.02f + p.centerpf[b*3 + (tid%3)];
      }
    }
    grid.sync();
  }

  /* ---------- chamfer (all 256 blocks, 512 threads) ---------- */
  {
    int id = blk;
    int dir, rem;
    if (id < 32){ dir=0; rem=id; }
    else if (id < 64){ dir=1; rem=id-32; }
    else if (id < 160){ dir=2; rem=id-64; }
    else { dir=3; rem=id-160; }
    int b, xb, yb;
    if (dir < 2){ b = rem>>3; int l = rem&7; xb = l>>2; yb = l&3; }
    else if (dir == 2){ b = rem/24; int l = rem%24; xb = l>>2; yb = l&3; }
    else { b = rem/24; int l = rem%24; xb = l/12; yb = l%12; }

    int Nx, Ny; const float* X; const float* Y; unsigned* mp;
    if (dir==0){      Nx=N0;   Ny=N0;   X=p.canvas+(size_t)b*NMAX*3;       Y=p.gt+(size_t)b*N0*3;            mp=p.minAB + b*N0; }
    else if (dir==1){ Nx=N0;   Ny=N0;   X=p.gt+(size_t)b*N0*3;             Y=p.canvas+(size_t)b*NMAX*3;      mp=p.minAB + BB*N0 + b*N0; }
    else if (dir==2){ Nx=NNEW; Ny=N0;   X=p.canvas+((size_t)b*NMAX+N0)*3;  Y=p.gt+(size_t)b*N0*3;            mp=p.minCD + b*NNEW; }
    else {            Nx=N0;   Ny=NNEW; X=p.gt+(size_t)b*N0*3;             Y=p.canvas+((size_t)b*NMAX+N0)*3; mp=p.minCD + BB*NNEW + b*N0; }

    int xbase = xb*2048;
    int ybase = yb*1024;
    int tn = min(1024, Ny - ybase);
    for (int tt=tid; tt<tn; tt+=512){
      const float* yp = Y + (size_t)(ybase+tt)*3;
      float y0=yp[0], y1=yp[1], y2=yp[2];
      sh.ch.y0[tt]=y0; sh.ch.y1[tt]=y1; sh.ch.y2[tt]=y2; sh.ch.ny[tt]=y0*y0+y1*y1+y2*y2;
    }
    __syncthreads();

    float X0[4],X1[4],X2[4],NXr[4],MN[4]; int XI[4]; bool VA[4];
#pragma unroll
    for (int q=0;q<4;q++){
      int x = xbase + q*512 + tid;
      VA[q] = x < Nx;
      int xc = VA[q] ? x : 0;
      const float* xp = X + (size_t)xc*3;
      X0[q]=xp[0]; X1[q]=xp[1]; X2[q]=xp[2];
      NXr[q] = X0[q]*X0[q] + X1[q]*X1[q] + X2[q]*X2[q];
      MN[q] = 3.4e38f; XI[q] = xc;
    }
    const float4* v0 = (const float4*)sh.ch.y0;
    const float4* v1 = (const float4*)sh.ch.y1;
    const float4* v2 = (const float4*)sh.ch.y2;
    const float4* vn = (const float4*)sh.ch.ny;
    int j4n = tn >> 2;
    for (int j=0;j<j4n;j++){
      float4 a0 = v0[j], a1 = v1[j], a2 = v2[j], an = vn[j];
#pragma unroll
      for (int e=0;e<4;e++){
        float y0 = ((const float*)&a0)[e];
        float y1 = ((const float*)&a1)[e];
        float y2 = ((const float*)&a2)[e];
        float ny = ((const float*)&an)[e];
#pragma unroll
        for (int q=0;q<4;q++){
          float dot = fmaf(X0[q], y0, fmaf(X1[q], y1, X2[q]*y2));
          MN[q] = fminf(MN[q], fmaf(-2.f, dot, ny));
        }
      }
    }
    for (int j=j4n*4; j<tn; j++){
      float y0=sh.ch.y0[j], y1=sh.ch.y1[j], y2=sh.ch.y2[j], ny=sh.ch.ny[j];
#pragma unroll
      for (int q=0;q<4;q++){
        float dot = fmaf(X0[q], y0, fmaf(X1[q], y1, X2[q]*y2));
        MN[q] = fminf(MN[q], fmaf(-2.f, dot, ny));
      }
    }
#pragma unroll
    for (int q=0;q<4;q++)
      if (VA[q]) atomicMin(&mp[XI[q]], enc_f(MN[q] + NXr[q]));
  }
  grid.sync();

  /* ---------- chamfer reduce (blocks 0..15) ---------- */
  if (blk < 16){
    int dir = blk>>2, b = blk&3;
    const unsigned* mp; int len;
    if (dir==0){      mp=p.minAB + b*N0;            len=N0; }
    else if (dir==1){ mp=p.minAB + BB*N0 + b*N0;    len=N0; }
    else if (dir==2){ mp=p.minCD + b*NNEW;          len=NNEW; }
    else {            mp=p.minCD + BB*NNEW + b*N0;  len=N0; }
    float v = 0.f;
    for (int i=tid;i<len;i+=512) v += dec_f(mp[i]);
    v = bsum(v, sh.r.red);
    if (tid==0) p.acc[blk] = v;
  }
  grid.sync();

  if (blk==0 && tid==0){
    float cd1 = 0.f, cd2 = 0.f;
    for (int b=0;b<BB;b++) cd1 += p.acc[b]/(float)N0 + p.acc[4+b]/(float)N0;
    for (int b=0;b<BB;b++) cd2 += p.acc[8+b]/(float)NNEW + p.acc[12+b]/(float)N0;
    p.out[0] = 0.1f*(cd1/BB) + 1.0f*(cd2/BB);
  }
}

extern "C" void kernel_launch(void* const* d_in, const int* in_sizes, int n_in,
                              void* d_out, int out_size, void* d_ws, size_t ws_size,
                              hipStream_t stream) {
  (void)in_sizes; (void)n_in; (void)out_size; (void)ws_size;
  float* ws = (float*)d_ws;
  P p;
  p.points = (const float*)d_in[0];
  p.gt     = (const float*)d_in[1];
  p.w1  = (const float*)d_in[2];  p.b1  = (const float*)d_in[3];
  p.w2  = (const float*)d_in[4];  p.b2  = (const float*)d_in[5];
  p.w3  = (const float*)d_in[6];  p.b3  = (const float*)d_in[7];
  p.aw1 = (const float*)d_in[8];  p.ab1 = (const float*)d_in[9];
  p.aw2 = (const float*)d_in[10]; p.ab2 = (const float*)d_in[11];
  p.wih = (const float*)d_in[12]; p.whh = (const float*)d_in[13];
  p.bih = (const float*)d_in[14]; p.bhh = (const float*)d_in[15];
  p.rw1 = (const float*)d_in[16]; p.rb1 = (const float*)d_in[17];
  p.rw2 = (const float*)d_in[18]; p.rb2 = (const float*)d_in[19];
  p.canvas   = ws + OFF_CANVAS;
  p.minAB    = (unsigned*)(ws + OFF_MINAB);
  p.minCD    = (unsigned*)(ws + OFF_MINCD);
  p.gmax     = (unsigned*)(ws + OFF_GMAX);
  p.h        = ws + OFF_H;
  p.c        = ws + OFF_C;
  p.acc      = ws + OFF_ACC;
  p.centerpf = ws + OFF_CENTER;
  p.w2t      = ws + OFF_W2T;
  p.part     = ws + OFF_PART;
  p.gpart    = ws + OFF_GPART;
  p.out      = (float*)d_out;

  void* args[] = { &p };
  hipLaunchCooperativeKernel((const void*)mega_kernel, dim3(256), dim3(512),
                             args, 0, stream);
}

// Round 7
// 1139.362 us; speedup vs baseline: 3.1720x; 3.1720x over previous
//
#include <hip/hip_runtime.h>
#include <math.h>

#define BB 4
#define N0 4096
#define NEWP 1152
#define GD 256
#define HD 128
#define KSEL 64
#define NSTEPS 10
#define NMAX (N0 + NSTEPS*NEWP)   /* 15616 */
#define NNEW (NSTEPS*NEWP)        /* 11520 */

/* ---- workspace layout (float offsets) ---- */
#define OFF_CANVAS 0
#define OFF_MINAB  (OFF_CANVAS + BB*NMAX*3)
#define OFF_MINCD  (OFF_MINAB + 2*BB*N0)
#define OFF_GMAX   (OFF_MINCD + BB*NNEW + BB*N0)
#define OFF_H      (OFF_GMAX + BB*GD)          /* 2 buffers */
#define OFF_C      (OFF_H + 2*BB*HD)           /* 2 buffers */
#define OFF_ACC    (OFF_C + 2*BB*HD)
#define OFF_CENTER (OFF_ACC + 16)
#define OFF_W2T    (OFF_CENTER + 32)
#define OFF_PART   (OFF_W2T + 128*64)          /* BB*32*8 */
#define OFF_GPART  (OFF_PART + BB*32*8)        /* 32*BB*512 */
#define WS_FLOATS  (OFF_GPART + 32*BB*512)

__device__ __forceinline__ unsigned enc_f(float f){
  unsigned u = __float_as_uint(f);
  return (u & 0x80000000u) ? ~u : (u | 0x80000000u);
}
__device__ __forceinline__ float dec_f(unsigned e){
  unsigned u = (e & 0x80000000u) ? (e & 0x7fffffffu) : ~e;
  return __uint_as_float(u);
}
__device__ __forceinline__ float sigm(float x){ return 1.f/(1.f+expf(-x)); }

/* generic block reductions (up to 16 waves) */
__device__ __forceinline__ float block_sum(float v, volatile float* red){
#pragma unroll
  for (int s=32;s>0;s>>=1) v += __shfl_down(v, s, 64);
  int lane = threadIdx.x & 63, w = threadIdx.x >> 6, nw = blockDim.x >> 6;
  __syncthreads();
  if (lane==0) red[w] = v;
  __syncthreads();
  if (w==0){
    float x = (lane < nw) ? red[lane] : 0.f;
#pragma unroll
    for (int s=8;s>0;s>>=1) x += __shfl_down(x, s, 64);
    if (lane==0) red[0] = x;
  }
  __syncthreads();
  float r = red[0];
  __syncthreads();
  return r;
}
__device__ __forceinline__ float block_max(float v, volatile float* red){
#pragma unroll
  for (int s=32;s>0;s>>=1) v = fmaxf(v, __shfl_down(v, s, 64));
  int lane = threadIdx.x & 63, w = threadIdx.x >> 6, nw = blockDim.x >> 6;
  __syncthreads();
  if (lane==0) red[w] = v;
  __syncthreads();
  if (w==0){
    float x = (lane < nw) ? red[lane] : -3.4e38f;
#pragma unroll
    for (int s=8;s>0;s>>=1) x = fmaxf(x, __shfl_down(x, s, 64));
    if (lane==0) red[0] = x;
  }
  __syncthreads();
  float r = red[0];
  __syncthreads();
  return r;
}

/* shared encoder body: 64 points in sP[192] -> atomicMax into gmax_b[256].
   512 threads, 8 waves. Verified bit-exact in mega round. */
__device__ __forceinline__ void enc64(
    const float* __restrict__ sP, float* __restrict__ sF1, float* __restrict__ sF2,
    const float* __restrict__ w1, const float* __restrict__ b1,
    const float* __restrict__ w2t, const float* __restrict__ b2,
    const float* __restrict__ w3, const float* __restrict__ b3,
    unsigned* __restrict__ gmax_b)
{
  int tid = threadIdx.x;
  int lane = tid & 63;
  int wv = __builtin_amdgcn_readfirstlane(tid >> 6);
  /* f1: pt = wv+8k, feature = lane */
#pragma unroll
  for (int k=0;k<8;k++){
    int pt = wv + 8*k;
    float p0 = sP[pt*3], p1 = sP[pt*3+1], p2 = sP[pt*3+2];
    float v = b1[lane] + p0*w1[lane] + p1*w1[64+lane] + p2*w1[128+lane];
    sF1[pt*65 + lane] = fmaxf(v, 0.f);
  }
  __syncthreads();
  /* f2: pt = lane, feat = wv+8k (wave-uniform w2t row -> scalar loads) */
#pragma unroll
  for (int k=0;k<16;k++){
    int feat = wv + 8*k;
    const float* wr = w2t + feat*64;
    float a2 = b2[feat];
#pragma unroll
    for (int kk=0;kk<64;kk++) a2 += sF1[lane*65 + kk]*wr[kk];
    sF2[lane*129 + feat] = fmaxf(a2, 0.f);
  }
  __syncthreads();
  /* f3: wave wv owns 32-output chunk wv, lane = pt */
  {
    float a3[32];
    const float* b3p = b3 + wv*32;
#pragma unroll
    for (int d=0;d<32;d++) a3[d] = b3p[d];
    for (int k=0;k<128;k++){
      float fk = sF2[lane*129 + k];
      const float* wr = w3 + k*256 + wv*32;   /* wave-uniform */
#pragma unroll
      for (int d=0;d<32;d++) a3[d] += fk*wr[d];
    }
#pragma unroll
    for (int d=0;d<32;d++){
      float v = a3[d];
#pragma unroll
      for (int s=32;s>0;s>>=1) v = fmaxf(v, __shfl_down(v, s, 64));
      if (lane==0) atomicMax(&gmax_b[wv*32 + d], enc_f(v));
    }
  }
}

/* ---------- init: canvas copy, min arrays, gmax, h/c, w2t ---------- */
__global__ __launch_bounds__(512) void init_kernel(
    const float* __restrict__ points, const float* __restrict__ w2,
    float* __restrict__ canvas, unsigned* __restrict__ minAB,
    unsigned* __restrict__ minCD, unsigned* __restrict__ gmax,
    float* __restrict__ h, float* __restrict__ c, float* __restrict__ w2t)
{
  int gid = blockIdx.x*512 + threadIdx.x;
  if (gid < BB*N0*3){
    int b = gid/(N0*3), r = gid - b*(N0*3);
    canvas[(size_t)b*NMAX*3 + r] = points[gid];
  }
  if (gid < 2*BB*N0) minAB[gid] = 0xFFFFFFFFu;
  if (gid < BB*NNEW + BB*N0) minCD[gid] = 0xFFFFFFFFu;
  if (gid < BB*GD) gmax[gid] = 0u;
  if (gid < 2*BB*HD){ h[gid]=0.f; c[gid]=0.f; }
  if (gid < 128*64){ int j=gid>>6, k=gid&63; w2t[gid] = w2[k*128+j]; }
}

/* ---------- enc0: encoder for initial points ---------- */
__global__ __launch_bounds__(512) void enc_kernel(
    const float* __restrict__ canvas,
    const float* __restrict__ w1, const float* __restrict__ b1,
    const float* __restrict__ w2t, const float* __restrict__ b2,
    const float* __restrict__ w3, const float* __restrict__ b3,
    unsigned* __restrict__ gmax)
{
  __shared__ float sP[192], sF1[64*65], sF2[64*129];
  int b = blockIdx.y, lg = blockIdx.x;
  int tid = threadIdx.x;
  if (tid < 192) sP[tid] = canvas[(size_t)b*NMAX*3 + (size_t)lg*192 + tid];
  __syncthreads();
  enc64(sP, sF1, sF2, w1, b1, w2t, b2, w3, b3, gmax + b*GD);
}

/* ---------- scores partials + lstm partials, one dispatch ---------- */
__global__ __launch_bounds__(512) void sl_kernel(
    const float* __restrict__ canvas, const float* __restrict__ aw1,
    const float* __restrict__ ab1, const float* __restrict__ aw2,
    const float* __restrict__ ab2, const unsigned* __restrict__ gmax,
    const float* __restrict__ h_in,
    const float* __restrict__ wih, const float* __restrict__ whh,
    float* __restrict__ part, float* __restrict__ gpart, int N, int nch)
{
  __shared__ float sBatt[128];
  __shared__ float red[16];
  __shared__ float sV[BB][12];
  int blk = blockIdx.x;
  int tid = threadIdx.x;
  if (blk < 4*nch){
    int b = blk / nch, ch = blk - b*nch;
    if (tid < 128){
      float a = ab1[tid];
      for (int k=0;k<GD;k++) a += dec_f(gmax[b*GD+k]) * aw1[(3+k)*128 + tid];
      for (int k=0;k<HD;k++) a += h_in[b*HD+k] * aw1[(3+GD+k)*128 + tid];
      sBatt[tid] = a;
    }
    __syncthreads();
    int i = ch*512 + tid;
    bool act = i < N;
    float p0=0.f,p1=0.f,p2=0.f,s=-3.4e38f;
    if (act){
      const float* pp = canvas + (size_t)(b*NMAX + i)*3;
      p0=pp[0]; p1=pp[1]; p2=pp[2];
      s = ab2[0];
      for (int j=0;j<128;j++){
        float v = sBatt[j] + p0*aw1[j] + p1*aw1[128+j] + p2*aw1[256+j];
        s += fmaxf(v, 0.f)*aw2[j];
      }
    }
    float mb = block_max(s, red);
    float e = act ? expf(s - mb) : 0.f;
    float se = block_sum(e, red);
    float wx = block_sum(e*p0, red);
    float wy = block_sum(e*p1, red);
    float wz = block_sum(e*p2, red);
    if (tid==0){
      float* pr = part + (size_t)(b*32 + ch)*8;
      pr[0]=mb; pr[1]=se; pr[2]=wx; pr[3]=wy; pr[4]=wz;
    }
  } else {
    int cc = blk - 4*nch;   /* 0..31 */
    if (tid < BB*12){
      int b = tid/12, j = tid - b*12;
      int r = cc*12 + j;
      sV[b][j] = (r < 256) ? dec_f(gmax[b*GD + r]) : h_in[b*HD + (r-256)];
    }
    __syncthreads();
    float a0=0.f,a1=0.f,a2=0.f,a3=0.f;
#pragma unroll
    for (int j=0;j<12;j++){
      int r = cc*12 + j;
      const float* wr = (r < 256) ? (wih + (size_t)r*512) : (whh + (size_t)(r-256)*512);
      float wvv = wr[tid];
      a0 += sV[0][j]*wvv; a1 += sV[1][j]*wvv;
      a2 += sV[2][j]*wvv; a3 += sV[3][j]*wvv;
    }
    float* gp = gpart + (size_t)cc*(BB*512);
    gp[0*512+tid]=a0; gp[1*512+tid]=a1; gp[2*512+tid]=a2; gp[3*512+tid]=a3;
  }
}

/* ---------- stepA: center + top-64 threshold + patch mean ---------- */
__global__ __launch_bounds__(1024) void stepA_kernel(
    const float* __restrict__ canvas, const float* __restrict__ part,
    float* __restrict__ centerpf, int N, int nch)
{
  __shared__ float red[16];
  __shared__ float sC[3];
  __shared__ unsigned cbufA[2][16];
  __shared__ unsigned cbufB[2][16];
  __shared__ int tieCnt;
  __shared__ int tieIdx[256];

  int b = blockIdx.x;
  int tid = threadIdx.x;
  int lane = tid & 63, wid = tid >> 6;
  const float* cv = canvas + (size_t)b*NMAX*3;

  float pm=-3.4e38f, pse=0.f, pwx=0.f, pwy=0.f, pwz=0.f;
  if (tid < nch){
    const float* pp = part + (size_t)(b*32 + tid)*8;
    pm=pp[0]; pse=pp[1]; pwx=pp[2]; pwy=pp[3]; pwz=pp[4];
  }
  float M = block_max(pm, red);
  float w = (tid < nch) ? expf(pm - M) : 0.f;
  float se = block_sum(pse*w, red);
  float wx = block_sum(pwx*w, red);
  float wy = block_sum(pwy*w, red);
  float wz = block_sum(pwz*w, red);
  if (tid==0){ sC[0]=wx/se; sC[1]=wy/se; sC[2]=wz/se; }
  __syncthreads();
  float cx=sC[0], cy=sC[1], cz=sC[2];
  if (tid<3) centerpf[b*3+tid] = sC[tid];

  unsigned ur[16];
#pragma unroll
  for (int q=0;q<16;q++){
    ur[q] = 0xFFFFFFFFu;
    int i = tid + q*1024;
    if (i < N){
      const float* p = cv + (size_t)i*3;
      float dx=p[0]-cx, dy=p[1]-cy, dz=p[2]-cz;
      ur[q] = __float_as_uint(dx*dx + dy*dy + dz*dz);
    }
  }

  unsigned T = 0u;
  int cntBelow = 0;
  int par = 0;
  {
    unsigned cand = 1u<<30;
    unsigned tc = 0;
#pragma unroll
    for (int q=0;q<16;q++) tc += (ur[q] < cand) ? 1u : 0u;
#pragma unroll
    for (int s=32;s>0;s>>=1) tc += __shfl_down(tc, s, 64);
    if (lane==0) cbufA[par][wid] = tc;
    __syncthreads();
    unsigned tot = 0;
#pragma unroll
    for (int i2=0;i2<16;i2++) tot += cbufA[par][i2];
    if ((int)tot < KSEL){ T = cand; cntBelow = (int)tot; }
    par ^= 1;
  }
  for (int bit=29; bit>=1; bit-=2){
    unsigned q1 = 1u<<(bit-1);
    unsigned c1 = T + q1, c2 = T + 2u*q1, c3 = T + 3u*q1;
    unsigned ta = 0, tb = 0;
#pragma unroll
    for (int q=0;q<16;q++){
      unsigned u = ur[q];
      ta += (u < c1 ? 1u : 0u) | (u < c2 ? 0x10000u : 0u);
      tb += (u < c3 ? 1u : 0u);
    }
#pragma unroll
    for (int s=32;s>0;s>>=1){ ta += __shfl_down(ta, s, 64); tb += __shfl_down(tb, s, 64); }
    if (lane==0){ cbufA[par][wid] = ta; cbufB[par][wid] = tb; }
    __syncthreads();
    unsigned sa = 0, sb = 0;
#pragma unroll
    for (int i2=0;i2<16;i2++){ sa += cbufA[par][i2]; sb += cbufB[par][i2]; }
    int n1 = (int)(sa & 0xFFFFu), n2 = (int)(sa >> 16), n3 = (int)sb;
    if (n3 < KSEL){ T = c3; cntBelow = n3; }
    else if (n2 < KSEL){ T = c2; cntBelow = n2; }
    else if (n1 < KSEL){ T = c1; cntBelow = n1; }
    par ^= 1;
  }
  int kneed = KSEL - cntBelow;

  if (tid==0) tieCnt = 0;
  __syncthreads();
  float sx=0.f, sy=0.f, sz=0.f;
#pragma unroll
  for (int q=0;q<16;q++){
    unsigned u = ur[q];
    if (u < T){
      const float* p = cv + (size_t)(tid + q*1024)*3;
      sx += p[0]; sy += p[1]; sz += p[2];
    } else if (u == T){
      int pos = atomicAdd(&tieCnt, 1);
      if (pos < 256) tieIdx[pos] = tid + q*1024;
    }
  }
  __syncthreads();
  sx = block_sum(sx, red);
  sy = block_sum(sy, red);
  sz = block_sum(sz, red);
  if (tid==0){
    int mm = tieCnt < 256 ? tieCnt : 256;
    for (int t=0;t<kneed;t++){
      int best=-1, bi=0x7fffffff;
      for (int q=0;q<mm;q++){ int v = tieIdx[q]; if (v < bi){ bi=v; best=q; } }
      if (best >= 0){
        tieIdx[best] = 0x7fffffff;
        const float* p = cv + (size_t)bi*3;
        sx += p[0]; sy += p[1]; sz += p[2];
      }
    }
    centerpf[16 + b*3 + 0] = sx/KSEL - cx;
    centerpf[16 + b*3 + 1] = sy/KSEL - cy;
    centerpf[16 + b*3 + 2] = sz/KSEL - cz;
  }
}

/* ---------- refine + encode the new 64-point tile, fused ---------- */
__global__ __launch_bounds__(512) void refine_enc_kernel(
    float* __restrict__ canvas, const float* __restrict__ gpart,
    const float* __restrict__ centerpf,
    const float* __restrict__ c_in, float* __restrict__ c_out,
    float* __restrict__ h_out,
    const float* __restrict__ wih,
    const float* __restrict__ bih, const float* __restrict__ bhh,
    const float* __restrict__ rw1, const float* __restrict__ rb1,
    const float* __restrict__ rw2, const float* __restrict__ rb2,
    const float* __restrict__ w1, const float* __restrict__ b1,
    const float* __restrict__ w2t, const float* __restrict__ b2,
    const float* __restrict__ w3, const float* __restrict__ b3,
    unsigned* __restrict__ gmax, int N)
{
  __shared__ float sG[512];
  __shared__ float sH[HD];
  __shared__ float sRf[HD];
  __shared__ float sP[192];
  __shared__ float sF1[64*65], sF2[64*129];
  int g = blockIdx.x, b = blockIdx.y;
  int tid = threadIdx.x;
  float cx = centerpf[b*3+0], cy = centerpf[b*3+1], cz = centerpf[b*3+2];
  float fx = centerpf[16+b*3+0], fy = centerpf[16+b*3+1], fz = centerpf[16+b*3+2];
  /* LSTM gate finish (redundant per block) */
  {
    float gg = bih[tid] + bhh[tid];
    for (int cc=0; cc<32; cc++) gg += gpart[(size_t)cc*(BB*512) + b*512 + tid];
    gg += cx*wih[(size_t)256*512+tid] + cy*wih[(size_t)257*512+tid] + cz*wih[(size_t)258*512+tid];
    gg += fx*wih[(size_t)259*512+tid] + fy*wih[(size_t)260*512+tid] + fz*wih[(size_t)261*512+tid];
    sG[tid] = gg;
  }
  __syncthreads();
  if (tid < HD){
    float gi=sG[tid], gf=sG[128+tid], gg2=sG[256+tid], go=sG[384+tid];
    float cn = sigm(gf)*c_in[b*HD+tid] + sigm(gi)*tanhf(gg2);
    float hn = sigm(go)*tanhf(cn);
    sH[tid] = hn;
    if (g==0){ c_out[b*HD+tid]=cn; h_out[b*HD+tid]=hn; }
  }
  __syncthreads();
  if (tid < HD){
    float a = rb1[tid];
    for (int k=0;k<HD;k++) a += sH[k]*rw1[k*HD + tid];
    sRf[tid] = fmaxf(a, 0.f);
  }
  __syncthreads();
  /* decoder: this block's 192 outputs = 64 points */
  if (tid < 192){
    int o = g*192 + tid;
    float a = rb2[o];
    for (int k=0;k<HD;k++) a += sRf[k]*rw2[(size_t)k*(NEWP*3) + o];
    float val = a*0.02f + centerpf[b*3 + (tid%3)];
    sP[tid] = val;
    canvas[((size_t)b*NMAX + N)*3 + o] = val;
  }
  __syncthreads();
  /* encode the freshly generated 64 points */
  enc64(sP, sF1, sF2, w1, b1, w2t, b2, w3, b3, gmax + b*GD);
}

/* ---------- chamfer (proven roofline config) ---------- */
__global__ __launch_bounds__(512) void chamfer_kernel(
    const float* __restrict__ canvas, const float* __restrict__ gt,
    unsigned* __restrict__ minAB, unsigned* __restrict__ minCD)
{
  __shared__ float sy0[1024], sy1[1024], sy2[1024], sny[1024];
  int id = blockIdx.x;
  int dir, rem;
  if (id < 32){ dir=0; rem=id; }
  else if (id < 64){ dir=1; rem=id-32; }
  else if (id < 160){ dir=2; rem=id-64; }
  else { dir=3; rem=id-160; }
  int b, xb, yb;
  if (dir < 2){ b = rem>>3; int l = rem&7; xb = l>>2; yb = l&3; }
  else if (dir == 2){ b = rem/24; int l = rem%24; xb = l>>2; yb = l&3; }
  else { b = rem/24; int l = rem%24; xb = l/12; yb = l%12; }

  int Nx, Ny; const float* X; const float* Y; unsigned* mp;
  if (dir==0){      Nx=N0;   Ny=N0;   X=canvas+(size_t)b*NMAX*3;       Y=gt+(size_t)b*N0*3;            mp=minAB + b*N0; }
  else if (dir==1){ Nx=N0;   Ny=N0;   X=gt+(size_t)b*N0*3;             Y=canvas+(size_t)b*NMAX*3;      mp=minAB + BB*N0 + b*N0; }
  else if (dir==2){ Nx=NNEW; Ny=N0;   X=canvas+((size_t)b*NMAX+N0)*3;  Y=gt+(size_t)b*N0*3;            mp=minCD + b*NNEW; }
  else {            Nx=N0;   Ny=NNEW; X=gt+(size_t)b*N0*3;             Y=canvas+((size_t)b*NMAX+N0)*3; mp=minCD + BB*NNEW + b*N0; }

  int xbase = xb*2048;
  int ybase = yb*1024;
  int tn = min(1024, Ny - ybase);
  int tid = threadIdx.x;
  for (int t=tid; t<tn; t+=512){
    const float* yp = Y + (size_t)(ybase+t)*3;
    float y0=yp[0], y1=yp[1], y2=yp[2];
    sy0[t]=y0; sy1[t]=y1; sy2[t]=y2; sny[t]=y0*y0+y1*y1+y2*y2;
  }
  __syncthreads();

  float X0[4],X1[4],X2[4],NXr[4],MN[4]; int XI[4]; bool VA[4];
#pragma unroll
  for (int q=0;q<4;q++){
    int x = xbase + q*512 + tid;
    VA[q] = x < Nx;
    int xc = VA[q] ? x : 0;
    const float* xp = X + (size_t)xc*3;
    X0[q]=xp[0]; X1[q]=xp[1]; X2[q]=xp[2];
    NXr[q] = X0[q]*X0[q] + X1[q]*X1[q] + X2[q]*X2[q];
    MN[q] = 3.4e38f; XI[q] = xc;
  }
  const float4* v0 = (const float4*)sy0;
  const float4* v1 = (const float4*)sy1;
  const float4* v2 = (const float4*)sy2;
  const float4* vn = (const float4*)sny;
  int j4n = tn >> 2;
  for (int j=0;j<j4n;j++){
    float4 a0 = v0[j], a1 = v1[j], a2 = v2[j], an = vn[j];
#pragma unroll
    for (int e=0;e<4;e++){
      float y0 = ((const float*)&a0)[e];
      float y1 = ((const float*)&a1)[e];
      float y2 = ((const float*)&a2)[e];
      float ny = ((const float*)&an)[e];
#pragma unroll
      for (int q=0;q<4;q++){
        float dot = fmaf(X0[q], y0, fmaf(X1[q], y1, X2[q]*y2));
        MN[q] = fminf(MN[q], fmaf(-2.f, dot, ny));
      }
    }
  }
  for (int j=j4n*4; j<tn; j++){
    float y0=sy0[j], y1=sy1[j], y2=sy2[j], ny=sny[j];
#pragma unroll
    for (int q=0;q<4;q++){
      float dot = fmaf(X0[q], y0, fmaf(X1[q], y1, X2[q]*y2));
      MN[q] = fminf(MN[q], fmaf(-2.f, dot, ny));
    }
  }
#pragma unroll
  for (int q=0;q<4;q++)
    if (VA[q]) atomicMin(&mp[XI[q]], enc_f(MN[q] + NXr[q]));
}

__global__ __launch_bounds__(256) void chamfer_reduce_kernel(
    const unsigned* __restrict__ minAB, const unsigned* __restrict__ minCD,
    float* __restrict__ acc)
{
  __shared__ float red[16];
  int s = blockIdx.x, dir = s>>2, b = s&3;
  const unsigned* mp; int len;
  if (dir==0){      mp=minAB + b*N0;            len=N0; }
  else if (dir==1){ mp=minAB + BB*N0 + b*N0;    len=N0; }
  else if (dir==2){ mp=minCD + b*NNEW;          len=NNEW; }
  else {            mp=minCD + BB*NNEW + b*N0;  len=N0; }
  float v = 0.f;
  for (int i=threadIdx.x;i<len;i+=256) v += dec_f(mp[i]);
  v = block_sum(v, red);
  if (threadIdx.x==0) acc[s] = v;
}

__global__ void finish_kernel(const float* __restrict__ acc, float* __restrict__ out)
{
  if (threadIdx.x == 0 && blockIdx.x == 0){
    float cd1 = 0.f, cd2 = 0.f;
    for (int b=0;b<BB;b++) cd1 += acc[b]/(float)N0 + acc[4+b]/(float)N0;
    for (int b=0;b<BB;b++) cd2 += acc[8+b]/(float)NNEW + acc[12+b]/(float)N0;
    out[0] = 0.1f*(cd1/BB) + 1.0f*(cd2/BB);
  }
}

extern "C" void kernel_launch(void* const* d_in, const int* in_sizes, int n_in,
                              void* d_out, int out_size, void* d_ws, size_t ws_size,
                              hipStream_t stream) {
  (void)in_sizes; (void)n_in; (void)out_size; (void)ws_size;
  const float* points   = (const float*)d_in[0];
  const float* gt       = (const float*)d_in[1];
  const float* enc_w1   = (const float*)d_in[2];
  const float* enc_b1   = (const float*)d_in[3];
  const float* enc_w2   = (const float*)d_in[4];
  const float* enc_b2   = (const float*)d_in[5];
  const float* enc_w3   = (const float*)d_in[6];
  const float* enc_b3   = (const float*)d_in[7];
  const float* att_w1   = (const float*)d_in[8];
  const float* att_b1   = (const float*)d_in[9];
  const float* att_w2   = (const float*)d_in[10];
  const float* att_b2   = (const float*)d_in[11];
  const float* lstm_wih = (const float*)d_in[12];
  const float* lstm_whh = (const float*)d_in[13];
  const float* lstm_bih = (const float*)d_in[14];
  const float* lstm_bhh = (const float*)d_in[15];
  const float* ref_w1   = (const float*)d_in[16];
  const float* ref_b1   = (const float*)d_in[17];
  const float* ref_w2   = (const float*)d_in[18];
  const float* ref_b2   = (const float*)d_in[19];
  float* out = (float*)d_out;

  float* ws       = (float*)d_ws;
  float* canvas   = ws + OFF_CANVAS;
  unsigned* minAB = (unsigned*)(ws + OFF_MINAB);
  unsigned* minCD = (unsigned*)(ws + OFF_MINCD);
  unsigned* gmaxp = (unsigned*)(ws + OFF_GMAX);
  float* hb       = ws + OFF_H;
  float* cb       = ws + OFF_C;
  float* acc      = ws + OFF_ACC;
  float* centerb  = ws + OFF_CENTER;
  float* w2t      = ws + OFF_W2T;
  float* partb    = ws + OFF_PART;
  float* gpartb   = ws + OFF_GPART;

  init_kernel<<<dim3(128), 512, 0, stream>>>(points, enc_w2, canvas, minAB, minCD, gmaxp, hb, cb, w2t);
  enc_kernel<<<dim3(64, BB), 512, 0, stream>>>(canvas, enc_w1, enc_b1, w2t, enc_b2, enc_w3, enc_b3, gmaxp);

  for (int t=0; t<NSTEPS; t++){
    int N   = N0 + t*NEWP;
    int nch = (N + 511) >> 9;
    float* h_in  = hb + (t&1)*BB*HD;
    float* h_out = hb + ((t+1)&1)*BB*HD;
    float* c_in  = cb + (t&1)*BB*HD;
    float* c_out = cb + ((t+1)&1)*BB*HD;
    sl_kernel<<<dim3(4*nch + 32), 512, 0, stream>>>(canvas, att_w1, att_b1, att_w2, att_b2,
                                                    gmaxp, h_in, lstm_wih, lstm_whh,
                                                    partb, gpartb, N, nch);
    stepA_kernel<<<dim3(BB), 1024, 0, stream>>>(canvas, partb, centerb, N, nch);
    refine_enc_kernel<<<dim3(18, BB), 512, 0, stream>>>(canvas, gpartb, centerb,
                                                        c_in, c_out, h_out,
                                                        lstm_wih, lstm_bih, lstm_bhh,
                                                        ref_w1, ref_b1, ref_w2, ref_b2,
                                                        enc_w1, enc_b1, w2t, enc_b2, enc_w3, enc_b3,
                                                        gmaxp, N);
  }

  chamfer_kernel<<<dim3(256), 512, 0, stream>>>(canvas, gt, minAB, minCD);
  chamfer_reduce_kernel<<<dim3(16), 256, 0, stream>>>(minAB, minCD, acc);
  finish_kernel<<<1, 64, 0, stream>>>(acc, out);
}

// Round 8
// 1111.526 us; speedup vs baseline: 3.2514x; 1.0250x over previous
//
#include <hip/hip_runtime.h>
#include <math.h>

#define BB 4
#define N0 4096
#define NEWP 1152
#define GD 256
#define HD 128
#define KSEL 64
#define NSTEPS 10
#define NMAX (N0 + NSTEPS*NEWP)   /* 15616 */
#define NNEW (NSTEPS*NEWP)        /* 11520 */

/* ---- workspace layout (float offsets) ---- */
#define OFF_CANVAS 0
#define OFF_MINAB  (OFF_CANVAS + BB*NMAX*3)
#define OFF_MINCD  (OFF_MINAB + 2*BB*N0)
#define OFF_GMAX   (OFF_MINCD + BB*NNEW + BB*N0)
#define OFF_H      (OFF_GMAX + BB*GD)          /* 2 buffers */
#define OFF_C      (OFF_H + 2*BB*HD)           /* 2 buffers */
#define OFF_ACC    (OFF_C + 2*BB*HD)
#define OFF_CENTER (OFF_ACC + 16)
#define OFF_PART   (OFF_CENTER + 32)           /* BB*32*8 */
#define OFF_GPART  (OFF_PART + BB*32*8)        /* 32*BB*512 */
#define WS_FLOATS  (OFF_GPART + 32*BB*512)

#define F1S 68    /* sF1 row stride (floats), float4-aligned, conflict-free */
#define F2SD 132  /* sF2 row stride */

__device__ __forceinline__ unsigned enc_f(float f){
  unsigned u = __float_as_uint(f);
  return (u & 0x80000000u) ? ~u : (u | 0x80000000u);
}
__device__ __forceinline__ float dec_f(unsigned e){
  unsigned u = (e & 0x80000000u) ? (e & 0x7fffffffu) : ~e;
  return __uint_as_float(u);
}
__device__ __forceinline__ float sigm(float x){ return 1.f/(1.f+expf(-x)); }

__device__ __forceinline__ float block_sum(float v, volatile float* red){
#pragma unroll
  for (int s=32;s>0;s>>=1) v += __shfl_down(v, s, 64);
  int lane = threadIdx.x & 63, w = threadIdx.x >> 6, nw = blockDim.x >> 6;
  __syncthreads();
  if (lane==0) red[w] = v;
  __syncthreads();
  if (w==0){
    float x = (lane < nw) ? red[lane] : 0.f;
#pragma unroll
    for (int s=8;s>0;s>>=1) x += __shfl_down(x, s, 64);
    if (lane==0) red[0] = x;
  }
  __syncthreads();
  float r = red[0];
  __syncthreads();
  return r;
}
__device__ __forceinline__ float block_max(float v, volatile float* red){
#pragma unroll
  for (int s=32;s>0;s>>=1) v = fmaxf(v, __shfl_down(v, s, 64));
  int lane = threadIdx.x & 63, w = threadIdx.x >> 6, nw = blockDim.x >> 6;
  __syncthreads();
  if (lane==0) red[w] = v;
  __syncthreads();
  if (w==0){
    float x = (lane < nw) ? red[lane] : -3.4e38f;
#pragma unroll
    for (int s=8;s>0;s>>=1) x = fmaxf(x, __shfl_down(x, s, 64));
    if (lane==0) red[0] = x;
  }
  __syncthreads();
  float r = red[0];
  __syncthreads();
  return r;
}

/* encoder body: 64 points in sP[192] -> atomicMax into gmax_b[256].
   512 threads / 8 waves. f2: kk-outer float4 LDS reads + contiguous
   scalar weights (wave w owns feats [16w,16w+16)). f3: float4 reads. */
__device__ __forceinline__ void enc64(
    const float* __restrict__ sP, float* __restrict__ sF1, float* __restrict__ sF2,
    const float* __restrict__ w1, const float* __restrict__ b1,
    const float* __restrict__ w2, const float* __restrict__ b2,
    const float* __restrict__ w3, const float* __restrict__ b3,
    unsigned* __restrict__ gmax_b)
{
  int tid = threadIdx.x;
  int lane = tid & 63;
  int wv = __builtin_amdgcn_readfirstlane(tid >> 6);
  /* f1: pt = wv+8k, feature = lane */
#pragma unroll
  for (int k=0;k<8;k++){
    int pt = wv + 8*k;
    float p0 = sP[pt*3], p1 = sP[pt*3+1], p2 = sP[pt*3+2];
    float v = b1[lane] + p0*w1[lane] + p1*w1[64+lane] + p2*w1[128+lane];
    sF1[pt*F1S + lane] = fmaxf(v, 0.f);
  }
  __syncthreads();
  /* f2: pt = lane, wave owns feats [wv*16, wv*16+16) */
  {
    float a[16];
    const float* b2p = b2 + wv*16;
#pragma unroll
    for (int k=0;k<16;k++) a[k] = b2p[k];
#pragma unroll
    for (int kk4=0; kk4<16; kk4++){
      float4 f4 = *(const float4*)&sF1[lane*F1S + kk4*4];
#pragma unroll
      for (int e=0;e<4;e++){
        float fk = ((const float*)&f4)[e];
        const float* wr = w2 + (kk4*4+e)*128 + wv*16;   /* wave-uniform, contiguous */
#pragma unroll
        for (int k=0;k<16;k++) a[k] += fk*wr[k];
      }
    }
#pragma unroll
    for (int k=0;k<16;k++) sF2[lane*F2SD + wv*16 + k] = fmaxf(a[k], 0.f);
  }
  __syncthreads();
  /* f3: wave owns 32-output chunk wv, lane = pt */
  {
    float a3[32];
    const float* b3p = b3 + wv*32;
#pragma unroll
    for (int d=0;d<32;d++) a3[d] = b3p[d];
#pragma unroll 8
    for (int k4=0; k4<32; k4++){
      float4 f4 = *(const float4*)&sF2[lane*F2SD + k4*4];
#pragma unroll
      for (int e=0;e<4;e++){
        float fk = ((const float*)&f4)[e];
        const float* wr = w3 + (k4*4+e)*256 + wv*32;    /* wave-uniform, contiguous */
#pragma unroll
        for (int d=0;d<32;d++) a3[d] += fk*wr[d];
      }
    }
#pragma unroll
    for (int d=0;d<32;d++){
      float v = a3[d];
#pragma unroll
      for (int s=32;s>0;s>>=1) v = fmaxf(v, __shfl_down(v, s, 64));
      if (lane==0) atomicMax(&gmax_b[wv*32 + d], enc_f(v));
    }
  }
}

/* ---------- init ---------- */
__global__ __launch_bounds__(512) void init_kernel(
    const float* __restrict__ points,
    float* __restrict__ canvas, unsigned* __restrict__ minAB,
    unsigned* __restrict__ minCD, unsigned* __restrict__ gmax,
    float* __restrict__ h, float* __restrict__ c)
{
  int gid = blockIdx.x*512 + threadIdx.x;
  if (gid < BB*N0*3){
    int b = gid/(N0*3), r = gid - b*(N0*3);
    canvas[(size_t)b*NMAX*3 + r] = points[gid];
  }
  if (gid < 2*BB*N0) minAB[gid] = 0xFFFFFFFFu;
  if (gid < BB*NNEW + BB*N0) minCD[gid] = 0xFFFFFFFFu;
  if (gid < BB*GD) gmax[gid] = 0u;
  if (gid < 2*BB*HD){ h[gid]=0.f; c[gid]=0.f; }
}

/* ---------- enc0: encoder for initial points ---------- */
__global__ __launch_bounds__(512) void enc_kernel(
    const float* __restrict__ canvas,
    const float* __restrict__ w1, const float* __restrict__ b1,
    const float* __restrict__ w2, const float* __restrict__ b2,
    const float* __restrict__ w3, const float* __restrict__ b3,
    unsigned* __restrict__ gmax)
{
  __shared__ __align__(16) float sP[192];
  __shared__ __align__(16) float sF1[64*F1S];
  __shared__ __align__(16) float sF2[64*F2SD];
  int b = blockIdx.y, lg = blockIdx.x;
  int tid = threadIdx.x;
  if (tid < 192) sP[tid] = canvas[(size_t)b*NMAX*3 + (size_t)lg*192 + tid];
  __syncthreads();
  enc64(sP, sF1, sF2, w1, b1, w2, b2, w3, b3, gmax + b*GD);
}

/* ---------- scores partials + lstm partials, one dispatch ---------- */
__global__ __launch_bounds__(512) void sl_kernel(
    const float* __restrict__ canvas, const float* __restrict__ aw1,
    const float* __restrict__ ab1, const float* __restrict__ aw2,
    const float* __restrict__ ab2, const unsigned* __restrict__ gmax,
    const float* __restrict__ h_in,
    const float* __restrict__ wih, const float* __restrict__ whh,
    float* __restrict__ part, float* __restrict__ gpart, int N, int nch)
{
  __shared__ float sBatt[128];
  __shared__ float red[16];
  __shared__ float sV[BB][12];
  int blk = blockIdx.x;
  int tid = threadIdx.x;
  if (blk < 4*nch){
    int b = blk / nch, ch = blk - b*nch;
    if (tid < 128){
      float a = ab1[tid];
      for (int k=0;k<GD;k++) a += dec_f(gmax[b*GD+k]) * aw1[(3+k)*128 + tid];
      for (int k=0;k<HD;k++) a += h_in[b*HD+k] * aw1[(3+GD+k)*128 + tid];
      sBatt[tid] = a;
    }
    __syncthreads();
    int i = ch*512 + tid;
    bool act = i < N;
    float p0=0.f,p1=0.f,p2=0.f,s=-3.4e38f;
    if (act){
      const float* pp = canvas + (size_t)(b*NMAX + i)*3;
      p0=pp[0]; p1=pp[1]; p2=pp[2];
      s = ab2[0];
      for (int j=0;j<128;j++){
        float v = sBatt[j] + p0*aw1[j] + p1*aw1[128+j] + p2*aw1[256+j];
        s += fmaxf(v, 0.f)*aw2[j];
      }
    }
    float mb = block_max(s, red);
    float e = act ? expf(s - mb) : 0.f;
    float se = block_sum(e, red);
    float wx = block_sum(e*p0, red);
    float wy = block_sum(e*p1, red);
    float wz = block_sum(e*p2, red);
    if (tid==0){
      float* pr = part + (size_t)(b*32 + ch)*8;
      pr[0]=mb; pr[1]=se; pr[2]=wx; pr[3]=wy; pr[4]=wz;
    }
  } else {
    int cc = blk - 4*nch;   /* 0..31 */
    if (tid < BB*12){
      int b = tid/12, j = tid - b*12;
      int r = cc*12 + j;
      sV[b][j] = (r < 256) ? dec_f(gmax[b*GD + r]) : h_in[b*HD + (r-256)];
    }
    __syncthreads();
    float a0=0.f,a1=0.f,a2=0.f,a3=0.f;
#pragma unroll
    for (int j=0;j<12;j++){
      int r = cc*12 + j;
      const float* wr = (r < 256) ? (wih + (size_t)r*512) : (whh + (size_t)(r-256)*512);
      float wvv = wr[tid];
      a0 += sV[0][j]*wvv; a1 += sV[1][j]*wvv;
      a2 += sV[2][j]*wvv; a3 += sV[3][j]*wvv;
    }
    float* gp = gpart + (size_t)cc*(BB*512);
    gp[0*512+tid]=a0; gp[1*512+tid]=a1; gp[2*512+tid]=a2; gp[3*512+tid]=a3;
  }
}

/* ---------- stepA: center + top-64 threshold + patch mean ---------- */
__global__ __launch_bounds__(1024) void stepA_kernel(
    const float* __restrict__ canvas, const float* __restrict__ part,
    float* __restrict__ centerpf, int N, int nch)
{
  __shared__ float red[16];
  __shared__ float sC[3];
  __shared__ unsigned cbufA[2][16];
  __shared__ unsigned cbufB[2][16];
  __shared__ int tieCnt;
  __shared__ int tieIdx[256];

  int b = blockIdx.x;
  int tid = threadIdx.x;
  int lane = tid & 63, wid = tid >> 6;
  const float* cv = canvas + (size_t)b*NMAX*3;

  float pm=-3.4e38f, pse=0.f, pwx=0.f, pwy=0.f, pwz=0.f;
  if (tid < nch){
    const float* pp = part + (size_t)(b*32 + tid)*8;
    pm=pp[0]; pse=pp[1]; pwx=pp[2]; pwy=pp[3]; pwz=pp[4];
  }
  float M = block_max(pm, red);
  float w = (tid < nch) ? expf(pm - M) : 0.f;
  float se = block_sum(pse*w, red);
  float wx = block_sum(pwx*w, red);
  float wy = block_sum(pwy*w, red);
  float wz = block_sum(pwz*w, red);
  if (tid==0){ sC[0]=wx/se; sC[1]=wy/se; sC[2]=wz/se; }
  __syncthreads();
  float cx=sC[0], cy=sC[1], cz=sC[2];
  if (tid<3) centerpf[b*3+tid] = sC[tid];

  unsigned ur[16];
#pragma unroll
  for (int q=0;q<16;q++){
    ur[q] = 0xFFFFFFFFu;
    int i = tid + q*1024;
    if (i < N){
      const float* p = cv + (size_t)i*3;
      float dx=p[0]-cx, dy=p[1]-cy, dz=p[2]-cz;
      ur[q] = __float_as_uint(dx*dx + dy*dy + dz*dz);
    }
  }

  unsigned T = 0u;
  int cntBelow = 0;
  int par = 0;
  {
    unsigned cand = 1u<<30;
    unsigned tc = 0;
#pragma unroll
    for (int q=0;q<16;q++) tc += (ur[q] < cand) ? 1u : 0u;
#pragma unroll
    for (int s=32;s>0;s>>=1) tc += __shfl_down(tc, s, 64);
    if (lane==0) cbufA[par][wid] = tc;
    __syncthreads();
    unsigned tot = 0;
#pragma unroll
    for (int i2=0;i2<16;i2++) tot += cbufA[par][i2];
    if ((int)tot < KSEL){ T = cand; cntBelow = (int)tot; }
    par ^= 1;
  }
  for (int bit=29; bit>=1; bit-=2){
    unsigned q1 = 1u<<(bit-1);
    unsigned c1 = T + q1, c2 = T + 2u*q1, c3 = T + 3u*q1;
    unsigned ta = 0, tb = 0;
#pragma unroll
    for (int q=0;q<16;q++){
      unsigned u = ur[q];
      ta += (u < c1 ? 1u : 0u) | (u < c2 ? 0x10000u : 0u);
      tb += (u < c3 ? 1u : 0u);
    }
#pragma unroll
    for (int s=32;s>0;s>>=1){ ta += __shfl_down(ta, s, 64); tb += __shfl_down(tb, s, 64); }
    if (lane==0){ cbufA[par][wid] = ta; cbufB[par][wid] = tb; }
    __syncthreads();
    unsigned sa = 0, sb = 0;
#pragma unroll
    for (int i2=0;i2<16;i2++){ sa += cbufA[par][i2]; sb += cbufB[par][i2]; }
    int n1 = (int)(sa & 0xFFFFu), n2 = (int)(sa >> 16), n3 = (int)sb;
    if (n3 < KSEL){ T = c3; cntBelow = n3; }
    else if (n2 < KSEL){ T = c2; cntBelow = n2; }
    else if (n1 < KSEL){ T = c1; cntBelow = n1; }
    par ^= 1;
  }
  int kneed = KSEL - cntBelow;

  if (tid==0) tieCnt = 0;
  __syncthreads();
  float sx=0.f, sy=0.f, sz=0.f;
#pragma unroll
  for (int q=0;q<16;q++){
    unsigned u = ur[q];
    if (u < T){
      const float* p = cv + (size_t)(tid + q*1024)*3;
      sx += p[0]; sy += p[1]; sz += p[2];
    } else if (u == T){
      int pos = atomicAdd(&tieCnt, 1);
      if (pos < 256) tieIdx[pos] = tid + q*1024;
    }
  }
  __syncthreads();
  sx = block_sum(sx, red);
  sy = block_sum(sy, red);
  sz = block_sum(sz, red);
  if (tid==0){
    int mm = tieCnt < 256 ? tieCnt : 256;
    for (int t=0;t<kneed;t++){
      int best=-1, bi=0x7fffffff;
      for (int q=0;q<mm;q++){ int v = tieIdx[q]; if (v < bi){ bi=v; best=q; } }
      if (best >= 0){
        tieIdx[best] = 0x7fffffff;
        const float* p = cv + (size_t)bi*3;
        sx += p[0]; sy += p[1]; sz += p[2];
      }
    }
    centerpf[16 + b*3 + 0] = sx/KSEL - cx;
    centerpf[16 + b*3 + 1] = sy/KSEL - cy;
    centerpf[16 + b*3 + 2] = sz/KSEL - cz;
  }
}

/* ---------- refine + encode the new 64-point tile, fused ---------- */
__global__ __launch_bounds__(512) void refine_enc_kernel(
    float* __restrict__ canvas, const float* __restrict__ gpart,
    const float* __restrict__ centerpf,
    const float* __restrict__ c_in, float* __restrict__ c_out,
    float* __restrict__ h_out,
    const float* __restrict__ wih,
    const float* __restrict__ bih, const float* __restrict__ bhh,
    const float* __restrict__ rw1, const float* __restrict__ rb1,
    const float* __restrict__ rw2, const float* __restrict__ rb2,
    const float* __restrict__ w1, const float* __restrict__ b1,
    const float* __restrict__ w2, const float* __restrict__ b2,
    const float* __restrict__ w3, const float* __restrict__ b3,
    unsigned* __restrict__ gmax, int N)
{
  __shared__ float sG[512];
  __shared__ float sH[HD];
  __shared__ float sRf[HD];
  __shared__ __align__(16) float sP[192];
  __shared__ __align__(16) float sF1[64*F1S];
  __shared__ __align__(16) float sF2[64*F2SD];
  int g = blockIdx.x, b = blockIdx.y;
  int tid = threadIdx.x;
  float cx = centerpf[b*3+0], cy = centerpf[b*3+1], cz = centerpf[b*3+2];
  float fx = centerpf[16+b*3+0], fy = centerpf[16+b*3+1], fz = centerpf[16+b*3+2];
  {
    float gg = bih[tid] + bhh[tid];
    for (int cc=0; cc<32; cc++) gg += gpart[(size_t)cc*(BB*512) + b*512 + tid];
    gg += cx*wih[(size_t)256*512+tid] + cy*wih[(size_t)257*512+tid] + cz*wih[(size_t)258*512+tid];
    gg += fx*wih[(size_t)259*512+tid] + fy*wih[(size_t)260*512+tid] + fz*wih[(size_t)261*512+tid];
    sG[tid] = gg;
  }
  __syncthreads();
  if (tid < HD){
    float gi=sG[tid], gf=sG[128+tid], gg2=sG[256+tid], go=sG[384+tid];
    float cn = sigm(gf)*c_in[b*HD+tid] + sigm(gi)*tanhf(gg2);
    float hn = sigm(go)*tanhf(cn);
    sH[tid] = hn;
    if (g==0){ c_out[b*HD+tid]=cn; h_out[b*HD+tid]=hn; }
  }
  __syncthreads();
  if (tid < HD){
    float a = rb1[tid];
    for (int k=0;k<HD;k++) a += sH[k]*rw1[k*HD + tid];
    sRf[tid] = fmaxf(a, 0.f);
  }
  __syncthreads();
  if (tid < 192){
    int o = g*192 + tid;
    float a = rb2[o];
    for (int k=0;k<HD;k++) a += sRf[k]*rw2[(size_t)k*(NEWP*3) + o];
    float val = a*0.02f + centerpf[b*3 + (tid%3)];
    sP[tid] = val;
    canvas[((size_t)b*NMAX + N)*3 + o] = val;
  }
  __syncthreads();
  enc64(sP, sF1, sF2, w1, b1, w2, b2, w3, b3, gmax + b*GD);
}

/* ---------- chamfer (proven roofline config) ---------- */
__global__ __launch_bounds__(512) void chamfer_kernel(
    const float* __restrict__ canvas, const float* __restrict__ gt,
    unsigned* __restrict__ minAB, unsigned* __restrict__ minCD)
{
  __shared__ float sy0[1024], sy1[1024], sy2[1024], sny[1024];
  int id = blockIdx.x;
  int dir, rem;
  if (id < 32){ dir=0; rem=id; }
  else if (id < 64){ dir=1; rem=id-32; }
  else if (id < 160){ dir=2; rem=id-64; }
  else { dir=3; rem=id-160; }
  int b, xb, yb;
  if (dir < 2){ b = rem>>3; int l = rem&7; xb = l>>2; yb = l&3; }
  else if (dir == 2){ b = rem/24; int l = rem%24; xb = l>>2; yb = l&3; }
  else { b = rem/24; int l = rem%24; xb = l/12; yb = l%12; }

  int Nx, Ny; const float* X; const float* Y; unsigned* mp;
  if (dir==0){      Nx=N0;   Ny=N0;   X=canvas+(size_t)b*NMAX*3;       Y=gt+(size_t)b*N0*3;            mp=minAB + b*N0; }
  else if (dir==1){ Nx=N0;   Ny=N0;   X=gt+(size_t)b*N0*3;             Y=canvas+(size_t)b*NMAX*3;      mp=minAB + BB*N0 + b*N0; }
  else if (dir==2){ Nx=NNEW; Ny=N0;   X=canvas+((size_t)b*NMAX+N0)*3;  Y=gt+(size_t)b*N0*3;            mp=minCD + b*NNEW; }
  else {            Nx=N0;   Ny=NNEW; X=gt+(size_t)b*N0*3;             Y=canvas+((size_t)b*NMAX+N0)*3; mp=minCD + BB*NNEW + b*N0; }

  int xbase = xb*2048;
  int ybase = yb*1024;
  int tn = min(1024, Ny - ybase);
  int tid = threadIdx.x;
  for (int t=tid; t<tn; t+=512){
    const float* yp = Y + (size_t)(ybase+t)*3;
    float y0=yp[0], y1=yp[1], y2=yp[2];
    sy0[t]=y0; sy1[t]=y1; sy2[t]=y2; sny[t]=y0*y0+y1*y1+y2*y2;
  }
  __syncthreads();

  float X0[4],X1[4],X2[4],NXr[4],MN[4]; int XI[4]; bool VA[4];
#pragma unroll
  for (int q=0;q<4;q++){
    int x = xbase + q*512 + tid;
    VA[q] = x < Nx;
    int xc = VA[q] ? x : 0;
    const float* xp = X + (size_t)xc*3;
    X0[q]=xp[0]; X1[q]=xp[1]; X2[q]=xp[2];
    NXr[q] = X0[q]*X0[q] + X1[q]*X1[q] + X2[q]*X2[q];
    MN[q] = 3.4e38f; XI[q] = xc;
  }
  const float4* v0 = (const float4*)sy0;
  const float4* v1 = (const float4*)sy1;
  const float4* v2 = (const float4*)sy2;
  const float4* vn = (const float4*)sny;
  int j4n = tn >> 2;
  for (int j=0;j<j4n;j++){
    float4 a0 = v0[j], a1 = v1[j], a2 = v2[j], an = vn[j];
#pragma unroll
    for (int e=0;e<4;e++){
      float y0 = ((const float*)&a0)[e];
      float y1 = ((const float*)&a1)[e];
      float y2 = ((const float*)&a2)[e];
      float ny = ((const float*)&an)[e];
#pragma unroll
      for (int q=0;q<4;q++){
        float dot = fmaf(X0[q], y0, fmaf(X1[q], y1, X2[q]*y2));
        MN[q] = fminf(MN[q], fmaf(-2.f, dot, ny));
      }
    }
  }
  for (int j=j4n*4; j<tn; j++){
    float y0=sy0[j], y1=sy1[j], y2=sy2[j], ny=sny[j];
#pragma unroll
    for (int q=0;q<4;q++){
      float dot = fmaf(X0[q], y0, fmaf(X1[q], y1, X2[q]*y2));
      MN[q] = fminf(MN[q], fmaf(-2.f, dot, ny));
    }
  }
#pragma unroll
  for (int q=0;q<4;q++)
    if (VA[q]) atomicMin(&mp[XI[q]], enc_f(MN[q] + NXr[q]));
}

__global__ __launch_bounds__(256) void chamfer_reduce_kernel(
    const unsigned* __restrict__ minAB, const unsigned* __restrict__ minCD,
    float* __restrict__ acc)
{
  __shared__ float red[16];
  int s = blockIdx.x, dir = s>>2, b = s&3;
  const unsigned* mp; int len;
  if (dir==0){      mp=minAB + b*N0;            len=N0; }
  else if (dir==1){ mp=minAB + BB*N0 + b*N0;    len=N0; }
  else if (dir==2){ mp=minCD + b*NNEW;          len=NNEW; }
  else {            mp=minCD + BB*NNEW + b*N0;  len=N0; }
  float v = 0.f;
  for (int i=threadIdx.x;i<len;i+=256) v += dec_f(mp[i]);
  v = block_sum(v, red);
  if (threadIdx.x==0) acc[s] = v;
}

__global__ void finish_kernel(const float* __restrict__ acc, float* __restrict__ out)
{
  if (threadIdx.x == 0 && blockIdx.x == 0){
    float cd1 = 0.f, cd2 = 0.f;
    for (int b=0;b<BB;b++) cd1 += acc[b]/(float)N0 + acc[4+b]/(float)N0;
    for (int b=0;b<BB;b++) cd2 += acc[8+b]/(float)NNEW + acc[12+b]/(float)N0;
    out[0] = 0.1f*(cd1/BB) + 1.0f*(cd2/BB);
  }
}

extern "C" void kernel_launch(void* const* d_in, const int* in_sizes, int n_in,
                              void* d_out, int out_size, void* d_ws, size_t ws_size,
                              hipStream_t stream) {
  (void)in_sizes; (void)n_in; (void)out_size; (void)ws_size;
  const float* points   = (const float*)d_in[0];
  const float* gt       = (const float*)d_in[1];
  const float* enc_w1   = (const float*)d_in[2];
  const float* enc_b1   = (const float*)d_in[3];
  const float* enc_w2   = (const float*)d_in[4];
  const float* enc_b2   = (const float*)d_in[5];
  const float* enc_w3   = (const float*)d_in[6];
  const float* enc_b3   = (const float*)d_in[7];
  const float* att_w1   = (const float*)d_in[8];
  const float* att_b1   = (const float*)d_in[9];
  const float* att_w2   = (const float*)d_in[10];
  const float* att_b2   = (const float*)d_in[11];
  const float* lstm_wih = (const float*)d_in[12];
  const float* lstm_whh = (const float*)d_in[13];
  const float* lstm_bih = (const float*)d_in[14];
  const float* lstm_bhh = (const float*)d_in[15];
  const float* ref_w1   = (const float*)d_in[16];
  const float* ref_b1   = (const float*)d_in[17];
  const float* ref_w2   = (const float*)d_in[18];
  const float* ref_b2   = (const float*)d_in[19];
  float* out = (float*)d_out;

  float* ws       = (float*)d_ws;
  float* canvas   = ws + OFF_CANVAS;
  unsigned* minAB = (unsigned*)(ws + OFF_MINAB);
  unsigned* minCD = (unsigned*)(ws + OFF_MINCD);
  unsigned* gmaxp = (unsigned*)(ws + OFF_GMAX);
  float* hb       = ws + OFF_H;
  float* cb       = ws + OFF_C;
  float* acc      = ws + OFF_ACC;
  float* centerb  = ws + OFF_CENTER;
  float* partb    = ws + OFF_PART;
  float* gpartb   = ws + OFF_GPART;

  init_kernel<<<dim3(128), 512, 0, stream>>>(points, canvas, minAB, minCD, gmaxp, hb, cb);
  enc_kernel<<<dim3(64, BB), 512, 0, stream>>>(canvas, enc_w1, enc_b1, enc_w2, enc_b2, enc_w3, enc_b3, gmaxp);

  for (int t=0; t<NSTEPS; t++){
    int N   = N0 + t*NEWP;
    int nch = (N + 511) >> 9;
    float* h_in  = hb + (t&1)*BB*HD;
    float* h_out = hb + ((t+1)&1)*BB*HD;
    float* c_in  = cb + (t&1)*BB*HD;
    float* c_out = cb + ((t+1)&1)*BB*HD;
    sl_kernel<<<dim3(4*nch + 32), 512, 0, stream>>>(canvas, att_w1, att_b1, att_w2, att_b2,
                                                    gmaxp, h_in, lstm_wih, lstm_whh,
                                                    partb, gpartb, N, nch);
    stepA_kernel<<<dim3(BB), 1024, 0, stream>>>(canvas, partb, centerb, N, nch);
    refine_enc_kernel<<<dim3(18, BB), 512, 0, stream>>>(canvas, gpartb, centerb,
                                                        c_in, c_out, h_out,
                                                        lstm_wih, lstm_bih, lstm_bhh,
                                                        ref_w1, ref_b1, ref_w2, ref_b2,
                                                        enc_w1, enc_b1, enc_w2, enc_b2, enc_w3, enc_b3,
                                                        gmaxp, N);
  }

  chamfer_kernel<<<dim3(256), 512, 0, stream>>>(canvas, gt, minAB, minCD);
  chamfer_reduce_kernel<<<dim3(16), 256, 0, stream>>>(minAB, minCD, acc);
  finish_kernel<<<1, 64, 0, stream>>>(acc, out);
}